// Round 4
// baseline (1628.725 us; speedup 1.0000x reference)
//
#include <hip/hip_runtime.h>
#include <math.h>

#define SS   96            // S
#define TM   96            // TM1
#define BB   8             // B
#define VV   32000         // V
#define EE   256           // E
#define HH   512           // H
#define NTOK (SS + TM)     // 192
#define G4   (4 * HH)      // 2048
#define NEGF (-1e30f)
#define LBLK 16            // k_lstm blocks (== barrier slots)

typedef __attribute__((ext_vector_type(8))) short short8;
typedef __attribute__((ext_vector_type(4))) float f32x4;
typedef unsigned long long u64;

// ---- workspace layout (float offsets) ----
#define XIH_OFF   ((size_t)0)
#define XIH_SZ    ((size_t)NTOK * BB * G4)       // 3,145,728 f
#define HALL_OFF  (XIH_OFF + XIH_SZ)
#define HALL_SZ   ((size_t)NTOK * BB * HH)       // 786,432 f
#define Q_OFF     (HALL_OFF + HALL_SZ)
#define Q_SZ      ((size_t)TM * BB * HH)         // 393,216 f
#define PPTR_OFF  (Q_OFF + Q_SZ)
#define ASENT_OFF (PPTR_OFF + (size_t)(TM * BB))
#define SSUM_OFF  (ASENT_OFF + (size_t)(TM * BB))
#define LSTAR_OFF (SSUM_OFF + (size_t)(TM * BB))
#define BAR_OFF   (LSTAR_OFF + (size_t)(TM * BB))   // 16 slots x 16 uints (64B spacing)
#define WHHBF_OFF (BAR_OFF + (size_t)1024)
#define WHHBF_SZF ((size_t)G4 * HH / 2)             // 524,288 f (2048x512 bf16)
#define HBF_OFF   (WHHBF_OFF + WHHBF_SZF)
#define HBF_SZF   ((size_t)2 * 16 * HH / 2)         // 8,192 f (2 x 16 x 512 bf16, dbuf)
#define ABF_OFF   (HBF_OFF + HBF_SZF)
#define ABF_SZF   ((size_t)(768 * HH) / 2)          // 196,608 f
#define WBF_OFF   (ABF_OFF + ABF_SZF)
#define WBF_SZF   ((size_t)VV * HH / 2)             // 8,192,000 f
#define NEED_F    (WBF_OFF + WBF_SZF)

__device__ __forceinline__ float sigf(float x) { return 1.f / (1.f + __expf(-x)); }

__device__ __forceinline__ unsigned short f2bf(float x) {
    unsigned bits = __float_as_uint(x);
    bits += 0x7FFFu + ((bits >> 16) & 1u);   // RNE
    return (unsigned short)(bits >> 16);
}

// ============ Kernel 1: Xih[tok][row] = emb_eff[idx[tok]] . W_ih[row] + b_ih[row]+b_hh[row]
__global__ void __launch_bounds__(256) k_xih(const int* __restrict__ src,
                                             const int* __restrict__ tgt,
                                             const float* __restrict__ emb,
                                             const float* __restrict__ Wih,
                                             const float* __restrict__ bih,
                                             const float* __restrict__ bhh,
                                             float* __restrict__ xih) {
    __shared__ float xs[16][EE];   // 16 KB
    const int tok0 = blockIdx.x * 16;
    const int row0 = blockIdx.y * 256;
    const int tid  = threadIdx.x;

    for (int e = tid; e < 16 * EE; e += 256) {
        int tk = e >> 8;          // EE == 256
        int k  = e & 255;
        int tau = tok0 + tk;
        int idx = (tau < SS * BB) ? src[tau] : tgt[tau - SS * BB];
        xs[tk][k] = (idx == 0) ? 0.f : emb[(size_t)idx * EE + k];   // PAD row zeroed
    }
    __syncthreads();

    const int row = row0 + tid;
    const float bias = bih[row] + bhh[row];
    float acc[16];
#pragma unroll
    for (int r = 0; r < 16; ++r) acc[r] = bias;

    const float4* w4 = (const float4*)(Wih + (size_t)row * EE);
    for (int k4 = 0; k4 < EE / 4; ++k4) {
        float4 w = w4[k4];
#pragma unroll
        for (int r = 0; r < 16; ++r) {
            float4 x = *((const float4*)&xs[r][k4 * 4]);   // broadcast across lanes
            acc[r] += w.x * x.x + w.y * x.y + w.z * x.z + w.w * x.w;
        }
    }
#pragma unroll
    for (int r = 0; r < 16; ++r)
        xih[(size_t)(tok0 + r) * G4 + row] = acc[r];
}

// ============ generic f32 -> bf16 converter (8 elems/thread) ============
__global__ void __launch_bounds__(256) k_cvt2(const float* __restrict__ src,
                                              unsigned short* __restrict__ dst,
                                              long n) {
    size_t base = ((size_t)blockIdx.x * 256 + threadIdx.x) * 8;
    if ((long)base >= n) return;
    float4 f0 = *(const float4*)(src + base);
    float4 f1 = *(const float4*)(src + base + 4);
    uint4 o;
    o.x = (unsigned)f2bf(f0.x) | ((unsigned)f2bf(f0.y) << 16);
    o.y = (unsigned)f2bf(f0.z) | ((unsigned)f2bf(f0.w) << 16);
    o.z = (unsigned)f2bf(f1.x) | ((unsigned)f2bf(f1.y) << 16);
    o.w = (unsigned)f2bf(f1.z) | ((unsigned)f2bf(f1.w) << 16);
    *(uint4*)(dst + base) = o;
}

// ============ Kernel 2: LSTM scan via MFMA, Whh register-resident ============
// 16 blocks x 256 thr (4 waves). Wave wv handles i in [blk*32 + wv*8, +8).
// Per wave: 2 MFMA tiles (T0 = gates i,f ; T1 = gates g,o) x 16 k-chunks.
// D layout: col = lane&15 = batch (8 real + 8 pad), row16 = 4*(lane>>4)+reg.
// h exchanged via h_bf (bf16, agent-scope write-through / cache-bypass loads),
// DOUBLE-BUFFERED by t-parity (fast block's t+1 publish can't clobber slow
// block's t read). Distributed 16-slot barrier, monotone generation.
__global__ void __launch_bounds__(256, 1) k_lstm(const float* __restrict__ xih,
                                                 const unsigned short* __restrict__ whhbf,
                                                 float* __restrict__ hall,
                                                 unsigned short* __restrict__ hbf,
                                                 unsigned* __restrict__ bar) {
    const int tid = threadIdx.x;
    const int wv  = tid >> 6;
    const int l   = tid & 63;
    const int b16 = l & 15;          // MFMA col = batch (pad >= 8)
    const int kg  = l >> 4;          // 0..3
    const int bb  = b16 & 7;         // clamped batch for (unused-pad) loads
    const int I0  = blockIdx.x * 32 + wv * 8;

    // ---- preload A fragments (Whh constant across all 192 steps) ----
    // A-frag row16 = j = l&15: T0 gate = j>>3 (i/f), T1 gate = 2+(j>>3) (g/o); i = I0+(j&7)
    const int j = b16;
    const size_t ar0 = ((size_t)((j >> 3) * HH + I0 + (j & 7))) * HH + kg * 8;
    const size_t ar1 = ((size_t)((2 + (j >> 3)) * HH + I0 + (j & 7))) * HH + kg * 8;
    short8 A0[16], A1[16];
#pragma unroll
    for (int ks = 0; ks < 16; ++ks) {
        A0[ks] = *(const short8*)(whhbf + ar0 + ks * 32);
        A1[ks] = *(const short8*)(whhbf + ar1 + ks * 32);
    }

    // zero the pad batch rows (8..15) of BOTH h_bf parity buffers (block 0,
    // before its first flag store -> visible to all readers at t>=1)
    if (blockIdx.x == 0) {
        u64* pad0 = (u64*)(hbf + 8 * HH);
        u64* pad1 = (u64*)(hbf + 16 * HH + 8 * HH);
        for (int e = tid; e < (8 * HH) / 4; e += 256) {
            __hip_atomic_store(pad0 + e, 0ULL, __ATOMIC_RELAXED, __HIP_MEMORY_SCOPE_AGENT);
            __hip_atomic_store(pad1 + e, 0ULL, __ATOMIC_RELAXED, __HIP_MEMORY_SCOPE_AGENT);
        }
    }

    // xih C-init addressing: lane (kg, reg r): row16 = 4*kg+r
    const int xgate0 = (kg >> 1);        // 0:i 1:f
    const int xgate1 = 2 + (kg >> 1);    // 2:g 3:o
    const int xi     = I0 + (kg & 1) * 4;

    float c0[4] = {0.f, 0.f, 0.f, 0.f};  // cell state for i = I0 + 4*kg + r (lanes l<32, b<8)

    for (int t = 0; t < NTOK; ++t) {
        // accumulator init = xih (MFMA C operand); pad cols read clamped batch (unused)
        const float* xbase = xih + ((size_t)t * BB + bb) * G4;
        float4 x0 = *(const float4*)(xbase + xgate0 * HH + xi);
        float4 x1 = *(const float4*)(xbase + xgate1 * HH + xi);
        f32x4 acc0 = {x0.x, x0.y, x0.z, x0.w};
        f32x4 acc1 = {x1.x, x1.y, x1.z, x1.w};

        if (t > 0) {
            // B fragments: h_{t-1} from parity buffer (t-1)&1, coherent loads (bypass L1/L2)
            const unsigned short* hsrc = hbf + ((t - 1) & 1) * (16 * HH) + b16 * HH + kg * 8;
            u64 blo[16], bhi[16];
#pragma unroll
            for (int ks = 0; ks < 16; ++ks) {
                const u64* bp = (const u64*)(hsrc + ks * 32);
                blo[ks] = __hip_atomic_load(bp,     __ATOMIC_RELAXED, __HIP_MEMORY_SCOPE_AGENT);
                bhi[ks] = __hip_atomic_load(bp + 1, __ATOMIC_RELAXED, __HIP_MEMORY_SCOPE_AGENT);
            }
#pragma unroll
            for (int ks = 0; ks < 16; ++ks) {
                union alignas(16) { u64 q[2]; short8 s; } u;
                u.q[0] = blo[ks]; u.q[1] = bhi[ks];
                acc0 = __builtin_amdgcn_mfma_f32_16x16x32_bf16(A0[ks], u.s, acc0, 0, 0, 0);
                acc1 = __builtin_amdgcn_mfma_f32_16x16x32_bf16(A1[ks], u.s, acc1, 0, 0, 0);
            }
        }

        // activations: lane (l<32) rows are i-gate (acc0) and g-gate (acc1);
        // f-gate / o-gate live at lane+32 (same i, same reg)
        float hreg[4];
#pragma unroll
        for (int r = 0; r < 4; ++r) {
            float gf = __shfl_down(acc0[r], 32, 64);
            float go = __shfl_down(acc1[r], 32, 64);
            float is = sigf(acc0[r]);
            float fs = sigf(gf);
            float gv = tanhf(acc1[r]);
            float os = sigf(go);
            c0[r] = fs * c0[r] + is * gv;
            hreg[r] = os * tanhf(c0[r]);
        }

        if (l < 32 && b16 < BB) {
            const int ib = I0 + kg * 4;   // kg in {0,1} here
            // f32 h for downstream kernels (plain cached stores; flushed at kernel end)
            *(float4*)(hall + ((size_t)t * BB + b16) * HH + ib) =
                make_float4(hreg[0], hreg[1], hreg[2], hreg[3]);
            // bf16 h for next step's B fragments (write-through to coherent point)
            u64 pk = (u64)f2bf(hreg[0]) | ((u64)f2bf(hreg[1]) << 16) |
                     ((u64)f2bf(hreg[2]) << 32) | ((u64)f2bf(hreg[3]) << 48);
            __hip_atomic_store((u64*)(hbf + (t & 1) * (16 * HH) + b16 * HH + ib), pk,
                               __ATOMIC_RELAXED, __HIP_MEMORY_SCOPE_AGENT);
        }

        if (t < NTOK - 1) {
            __syncthreads();   // all waves drain publishes (vmcnt0 before s_barrier)
            const unsigned tgt = (unsigned)(t + 1);
            if (tid == 0)
                __hip_atomic_store(&bar[(size_t)blockIdx.x * 16], tgt,
                                   __ATOMIC_RELAXED, __HIP_MEMORY_SCOPE_AGENT);
            if (tid < LBLK)
                while (__hip_atomic_load(&bar[(size_t)tid * 16], __ATOMIC_RELAXED,
                                         __HIP_MEMORY_SCOPE_AGENT) < tgt) {}
            __syncthreads();
        }
    }
}

// ============ Kernel 3: Q = tanh(Hdec @ W_att^T). grid TM, block 256 ============
__global__ void __launch_bounds__(256) k_q(const float* __restrict__ hall,
                                           const float* __restrict__ Watt,
                                           float* __restrict__ q) {
    __shared__ float hb[8 * 516];
    const int t = blockIdx.x, tid = threadIdx.x;
    const float* hdec = hall + (size_t)(SS + t) * (BB * HH);
    for (int e = tid; e < BB * HH; e += 256)
        hb[(e >> 9) * 516 + (e & 511)] = hdec[e];
    __syncthreads();

    for (int oi = tid; oi < BB * HH; oi += 256) {
        int b = oi & 7, ii = oi >> 3;
        const float4* w4 = (const float4*)(Watt + (size_t)ii * HH);
        const float4* h4 = (const float4*)(hb + b * 516);
        float acc = 0.f;
        for (int k4 = 0; k4 < HH / 4; ++k4) {
            float4 w = w4[k4], h = h4[k4];
            acc += w.x * h.x + w.y * h.y + w.z * h.z + w.w * h.w;
        }
        q[(size_t)(t * BB + b) * HH + ii] = tanhf(acc);
    }
}

// ============ Kernel 4: attention scores + softmax + pointer gather ============
__global__ void __launch_bounds__(256) k_att(const float* __restrict__ hall,
                                             const float* __restrict__ q,
                                             const float* __restrict__ sent,
                                             const int* __restrict__ src,
                                             const int* __restrict__ tgt,
                                             float* __restrict__ pptr,
                                             float* __restrict__ asent) {
    __shared__ float qs[HH];
    __shared__ float av[256];
    __shared__ float red[256];
    const int t = blockIdx.x, b = blockIdx.y, tid = threadIdx.x;

    for (int e = tid; e < HH; e += 256) qs[e] = q[(size_t)(t * BB + b) * HH + e];
    __syncthreads();

    const int j = tid;
    float acc = NEGF;
    if (j < SS + TM + 1) {
        bool valid = (j < SS + t + 1) || (j == SS + TM);
        if (valid) {
            const float* vptr = (j < SS + TM) ? (hall + (size_t)(j * BB + b) * HH) : sent;
            const float4* v4 = (const float4*)vptr;
            const float4* q4 = (const float4*)qs;
            float a = 0.f;
            for (int k4 = 0; k4 < HH / 4; ++k4) {
                float4 v = v4[k4], qq = q4[k4];
                a += v.x * qq.x + v.y * qq.y + v.z * qq.z + v.w * qq.w;
            }
            acc = a;
        }
    }
    red[tid] = acc;
    __syncthreads();
    for (int s2 = 128; s2 > 0; s2 >>= 1) {
        if (tid < s2) red[tid] = fmaxf(red[tid], red[tid + s2]);
        __syncthreads();
    }
    float m = red[0];
    __syncthreads();
    float e = __expf(acc - m);
    red[tid] = e;
    __syncthreads();
    for (int s2 = 128; s2 > 0; s2 >>= 1) {
        if (tid < s2) red[tid] += red[tid + s2];
        __syncthreads();
    }
    float denom = red[0];
    __syncthreads();
    float a = e / denom;
    av[tid] = a;
    __syncthreads();

    const int vs = tgt[(t + 1) * BB + b];
    float contrib = 0.f;
    if (j < SS) {
        if (src[j * BB + b] == vs) contrib += av[j];        // a_src
        if (tgt[j * BB + b] == vs) contrib += av[SS + j];   // a_tgt
    }
    red[tid] = contrib;
    __syncthreads();
    for (int s2 = 128; s2 > 0; s2 >>= 1) {
        if (tid < s2) red[tid] += red[tid + s2];
        __syncthreads();
    }
    if (tid == 0) {
        pptr[t * BB + b]  = red[0];
        asent[t * BB + b] = av[SS + TM];
    }
}

// ============ Kernel 5: vocab softmax stats via bf16 MFMA ============
__global__ void __launch_bounds__(256) k_vocab_mfma(const unsigned short* __restrict__ Abf,
                                                    const unsigned short* __restrict__ Wbf,
                                                    const int* __restrict__ tgt,
                                                    float* __restrict__ ssum,
                                                    float* __restrict__ lstar) {
    const int tid  = threadIdx.x;
    const int wave = tid >> 6;
    const int lane = tid & 63;
    const int r16  = lane & 15;
    const int kg   = lane >> 4;          // 0..3
    const int n0   = blockIdx.x * 64;

    const unsigned short* b0 = Wbf + (size_t)(n0 +  0 + r16) * HH + kg * 8;
    const unsigned short* b1 = Wbf + (size_t)(n0 + 16 + r16) * HH + kg * 8;
    const unsigned short* b2 = Wbf + (size_t)(n0 + 32 + r16) * HH + kg * 8;
    const unsigned short* b3 = Wbf + (size_t)(n0 + 48 + r16) * HH + kg * 8;

    for (int pass = 0; pass < 12; ++pass) {
        const int row0 = pass * 64 + wave * 16;
        const unsigned short* arow = Abf + (size_t)(row0 + r16) * HH + kg * 8;

        f32x4 acc0 = {0.f,0.f,0.f,0.f}, acc1 = acc0, acc2 = acc0, acc3 = acc0;
#pragma unroll
        for (int ks = 0; ks < 16; ++ks) {
            short8 a = *(const short8*)(arow + ks * 32);
            acc0 = __builtin_amdgcn_mfma_f32_16x16x32_bf16(a, *(const short8*)(b0 + ks * 32), acc0, 0, 0, 0);
            acc1 = __builtin_amdgcn_mfma_f32_16x16x32_bf16(a, *(const short8*)(b1 + ks * 32), acc1, 0, 0, 0);
            acc2 = __builtin_amdgcn_mfma_f32_16x16x32_bf16(a, *(const short8*)(b2 + ks * 32), acc2, 0, 0, 0);
            acc3 = __builtin_amdgcn_mfma_f32_16x16x32_bf16(a, *(const short8*)(b3 + ks * 32), acc3, 0, 0, 0);
        }

#pragma unroll
        for (int reg = 0; reg < 4; ++reg) {
            const int rowg = row0 + 4 * kg + reg;
            const int vs = tgt[BB + rowg];
            int cg;
            cg = n0 +  0 + r16; if (cg == vs) lstar[rowg] = acc0[reg];
            cg = n0 + 16 + r16; if (cg == vs) lstar[rowg] = acc1[reg];
            cg = n0 + 32 + r16; if (cg == vs) lstar[rowg] = acc2[reg];
            cg = n0 + 48 + r16; if (cg == vs) lstar[rowg] = acc3[reg];

            float v = __expf(acc0[reg]) + __expf(acc1[reg]) +
                      __expf(acc2[reg]) + __expf(acc3[reg]);
            v += __shfl_xor(v, 1, 64);
            v += __shfl_xor(v, 2, 64);
            v += __shfl_xor(v, 4, 64);
            v += __shfl_xor(v, 8, 64);
            if (r16 == 0) atomicAdd(&ssum[rowg], v);
        }
    }
}

// ============ Kernel 5-fallback: f32 vocab stats (used if ws too small) ============
__global__ void __launch_bounds__(256) k_vocab_f32(const float* __restrict__ hall,
                                                   const float* __restrict__ Wread,
                                                   const int* __restrict__ tgt,
                                                   float* __restrict__ ssum,
                                                   float* __restrict__ lstar) {
    __shared__ float hs[32 * HH];   // 64 KB
    const int tid = threadIdx.x;
    const int v0 = blockIdx.x * 512 + tid * 2;
    const int v1 = v0 + 1;
    const bool g0 = v0 < VV, g1 = v1 < VV;
    const float4* w40 = (const float4*)(Wread + (size_t)(g0 ? v0 : 0) * HH);
    const float4* w41 = (const float4*)(Wread + (size_t)(g1 ? v1 : 0) * HH);
    const int rbase0 = blockIdx.y * 128;

    for (int ch = 0; ch < 4; ++ch) {
        const int rbase = rbase0 + ch * 32;
        const float4* sp4 = (const float4*)(hall + ((size_t)SS * BB + rbase) * HH);
        float4* hs4 = (float4*)hs;
        for (int e = tid; e < 32 * HH / 4; e += 256) hs4[e] = sp4[e];
        __syncthreads();

        float acc0[32], acc1[32];
#pragma unroll
        for (int r = 0; r < 32; ++r) { acc0[r] = 0.f; acc1[r] = 0.f; }

        for (int k4 = 0; k4 < HH / 4; ++k4) {
            float4 w0 = w40[k4];
            float4 w1 = w41[k4];
#pragma unroll
            for (int r = 0; r < 32; ++r) {
                float4 h = *((const float4*)(hs + r * HH + k4 * 4));
                acc0[r] += w0.x * h.x + w0.y * h.y + w0.z * h.z + w0.w * h.w;
                acc1[r] += w1.x * h.x + w1.y * h.y + w1.z * h.z + w1.w * h.w;
            }
        }

#pragma unroll
        for (int r = 0; r < 32; ++r) {
            const int row = rbase + r;
            float val = 0.f;
            if (g0) val += __expf(acc0[r]);
            if (g1) val += __expf(acc1[r]);
#pragma unroll
            for (int d = 32; d > 0; d >>= 1) val += __shfl_xor(val, d, 64);
            if ((tid & 63) == 0) atomicAdd(&ssum[row], val);
            const int vs = tgt[row + BB];
            if (g0 && v0 == vs) lstar[row] = acc0[r];
            else if (g1 && v1 == vs) lstar[row] = acc1[r];
        }
        __syncthreads();
    }
}

// ============ Kernel 6: gold log-likelihoods + per-batch sums ============
__global__ void __launch_bounds__(768) k_final(const float* __restrict__ pptr,
                                               const float* __restrict__ asent,
                                               const float* __restrict__ ssum,
                                               const float* __restrict__ lstar,
                                               const int* __restrict__ tgt,
                                               float* __restrict__ out) {
    __shared__ float g[TM * BB], gp[TM * BB];
    const int tid = threadIdx.x;          // = t*8+b
    const int vs = tgt[tid + BB];
    const float pv = __expf(lstar[tid]) / ssum[tid];
    const float ps = pptr[tid];
    const float as = asent[tid];
    if (vs != 0) {
        g[tid]  = logf(ps + pv * as);
        gp[tid] = logf(ps + as);
    } else {
        g[tid] = 0.f; gp[tid] = 0.f;
    }
    __syncthreads();
    if (tid < BB) {
        float s1 = 0.f, s2 = 0.f;
        for (int t = 0; t < TM; ++t) { s1 += g[t * BB + tid]; s2 += gp[t * BB + tid]; }
        out[tid] = s1;
        out[BB + tid] = s2;
    }
}

extern "C" void kernel_launch(void* const* d_in, const int* in_sizes, int n_in,
                              void* d_out, int out_size, void* d_ws, size_t ws_size,
                              hipStream_t stream) {
    (void)in_sizes; (void)n_in; (void)out_size;
    const int*   src   = (const int*)d_in[0];
    const int*   tgt   = (const int*)d_in[1];
    const float* emb   = (const float*)d_in[2];
    const float* Wih   = (const float*)d_in[3];
    const float* Whh   = (const float*)d_in[4];
    const float* bih   = (const float*)d_in[5];
    const float* bhh   = (const float*)d_in[6];
    const float* Watt  = (const float*)d_in[7];
    const float* sent  = (const float*)d_in[8];
    const float* Wread = (const float*)d_in[9];
    float* ws  = (float*)d_ws;
    float* out = (float*)d_out;

    const bool use_mfma_vocab = ws_size >= NEED_F * sizeof(float);

    // zero SSUM + LSTAR + BAR (contiguous)
    hipMemsetAsync((void*)(ws + SSUM_OFF), 0,
                   (size_t)(TM * BB * 2 + 1024) * sizeof(float), stream);

    k_xih<<<dim3(NTOK * BB / 16, G4 / 256), 256, 0, stream>>>(
        src, tgt, emb, Wih, bih, bhh, ws + XIH_OFF);

    // Whh -> bf16 (needed by k_lstm)
    k_cvt2<<<dim3((unsigned)((size_t)G4 * HH / 8 / 256)), 256, 0, stream>>>(
        Whh, (unsigned short*)(ws + WHHBF_OFF), (long)G4 * HH);

    {
        const float* xih = ws + XIH_OFF;
        const unsigned short* whhbf = (const unsigned short*)(ws + WHHBF_OFF);
        float* hall = ws + HALL_OFF;
        unsigned short* hbf = (unsigned short*)(ws + HBF_OFF);
        unsigned* bar = (unsigned*)(ws + BAR_OFF);
        void* args[] = { (void*)&xih, (void*)&whhbf, (void*)&hall, (void*)&hbf, (void*)&bar };
        hipLaunchCooperativeKernel((void*)k_lstm, dim3(LBLK), dim3(256), args, 0, stream);
    }

    k_q<<<dim3(TM), 256, 0, stream>>>(ws + HALL_OFF, Watt, ws + Q_OFF);

    k_att<<<dim3(TM, BB), 256, 0, stream>>>(ws + HALL_OFF, ws + Q_OFF, sent,
                                            src, tgt, ws + PPTR_OFF, ws + ASENT_OFF);

    if (use_mfma_vocab) {
        k_cvt2<<<dim3((unsigned)((size_t)VV * HH / 8 / 256)), 256, 0, stream>>>(
            Wread, (unsigned short*)(ws + WBF_OFF), (long)VV * HH);
        k_cvt2<<<dim3((unsigned)((size_t)768 * HH / 8 / 256)), 256, 0, stream>>>(
            ws + HALL_OFF + (size_t)SS * BB * HH, (unsigned short*)(ws + ABF_OFF),
            (long)768 * HH);
        k_vocab_mfma<<<dim3(VV / 64), 256, 0, stream>>>(
            (const unsigned short*)(ws + ABF_OFF),
            (const unsigned short*)(ws + WBF_OFF),
            tgt, ws + SSUM_OFF, ws + LSTAR_OFF);
    } else {
        k_vocab_f32<<<dim3(63, 6), 256, 0, stream>>>(ws + HALL_OFF, Wread, tgt,
                                                     ws + SSUM_OFF, ws + LSTAR_OFF);
    }

    k_final<<<dim3(1), dim3(TM * BB), 0, stream>>>(ws + PPTR_OFF, ws + ASENT_OFF,
                                                   ws + SSUM_OFF, ws + LSTAR_OFF,
                                                   tgt, out);
}